// Round 20
// baseline (338.404 us; speedup 1.0000x reference)
//
#include <hip/hip_runtime.h>
#include <cstdint>
#include <cstddef>

// ---------------- problem constants (fixed by setup_inputs; k==32 always) ----
constexpr int B_SZ  = 256;
constexpr int T_SZ  = 8;
constexpr int DIN   = 768;
constexpr int DSAE  = 8192;
constexpr int KSEL  = 32;
constexpr int NROWS = B_SZ * T_SZ;        // 2048 (row r = b*T + t)
constexpr int CAND_CAP = 64;
constexpr int RCAP  = 32;                 // boundary-window capacity
constexpr float EPS_W = 5.5e-4f;          // covers dot-err + bf16-pre quant
constexpr int NSK   = DIN / 32;           // 24 K-steps

// ---------------- workspace layout (units: 4-byte words) ---------------------
constexpr size_t XC_SZ    = (size_t)NROWS * DIN;            // 1,572,864 w
constexpr size_t OFF_XC   = 0;
constexpr size_t OFF_XCP  = OFF_XC + XC_SZ;                 // packed bf16 xc
constexpr size_t XCP_W    = XC_SZ / 2;
constexpr size_t OFF_PREB = OFF_XCP + XCP_W;                // bf16 pre scratch
constexpr size_t PREB_W   = (size_t)NROWS * DSAE / 2;       // 8,388,608 w (32 MB)
constexpr size_t OFF_BIG  = OFF_PREB + PREB_W;
constexpr size_t BIG_W    = (size_t)T_SZ * DSAE * DIN / 2;  // 25,165,824 w
constexpr size_t WS_FAST_WORDS = OFF_BIG + BIG_W;           // ~144 MB

typedef short bf16x8 __attribute__((ext_vector_type(8)));  // 8 bf16 = 4 VGPR
typedef float f32x4  __attribute__((ext_vector_type(4)));

__device__ inline unsigned rne1(float x) {
  unsigned u = __float_as_uint(x);
  return (u + 0x7FFFu + ((u >> 16) & 1u)) >> 16;
}
__device__ inline float bf16tof(unsigned short v) {
  return __uint_as_float((unsigned)v << 16);
}
__device__ inline unsigned packtr(float a, float b) {
  return (__float_as_uint(a) >> 16) | (__float_as_uint(b) & 0xFFFF0000u);
}
__device__ inline void gload_lds16(const void* g, void* l) {
  __builtin_amdgcn_global_load_lds(
      (const __attribute__((address_space(1))) void*)g,
      (__attribute__((address_space(3))) void*)l, 16, 0, 0);
}

// ---------------- k_init: u-zero + loss-zero + xc/xcp (role by blockIdx) -----
// blocks [0,2048): zero the u region (linear float4 fill).
// blocks [2048,2816): xc = x - b_dec; xcp = fragment-packed bf16(xc).
__global__ __launch_bounds__(256) void k_init(const float* __restrict__ x,
                                              const float* __restrict__ bdec,
                                              float* __restrict__ xc,
                                              unsigned short* __restrict__ xcp,
                                              float* __restrict__ u,
                                              float* __restrict__ loss) {
  const int tid = threadIdx.x;
  if (blockIdx.x < 2048) {
    if (blockIdx.x == 0 && tid == 0) *loss = 0.f;
    const size_t base = (size_t)(blockIdx.x * 256 + tid) * 4;
    const size_t stride = (size_t)2048 * 256 * 4;
    const float4 z = {0.f, 0.f, 0.f, 0.f};
    for (size_t i = base; i < (size_t)NROWS * DSAE; i += stride)
      *(float4*)(u + i) = z;
    return;
  }
  const int c = (blockIdx.x - 2048) * 256 + tid;  // 0 .. 196607
  const int lane = c & 63;
  const int uu = c >> 6;
  const int s  = uu % NSK;
  const int tt = (uu / NSK) & (T_SZ - 1);
  const int gm = uu / (NSK * T_SZ);               // 0..15
  const int b  = gm * 16 + (lane & 15);
  const int k0 = s * 32 + (lane >> 4) * 8;
  const size_t rowOff = ((size_t)(b * T_SZ + tt)) * DIN + k0;
  float4 v0 = *(const float4*)(x + rowOff);
  float4 v1 = *(const float4*)(x + rowOff + 4);
  float4 d0 = *(const float4*)(bdec + tt * DIN + k0);
  float4 d1 = *(const float4*)(bdec + tt * DIN + k0 + 4);
  v0.x -= d0.x; v0.y -= d0.y; v0.z -= d0.z; v0.w -= d0.w;
  v1.x -= d1.x; v1.y -= d1.y; v1.z -= d1.z; v1.w -= d1.w;
  *(float4*)(xc + rowOff) = v0;
  *(float4*)(xc + rowOff + 4) = v1;
  uint4 p;
  p.x = rne1(v0.x) | (rne1(v0.y) << 16);
  p.y = rne1(v0.z) | (rne1(v0.w) << 16);
  p.z = rne1(v1.x) | (rne1(v1.y) << 16);
  p.w = rne1(v1.z) | (rne1(v1.w) << 16);
  *(uint4*)(xcp + (size_t)c * 8) = p;
}

// ---------------- fused encoder + W_dec transpose (independent roles) --------
// blocks [0,512): r11/r19 encoder (latency-bound, ~22% BW solo).
// blocks [512,512+3072): 128x128 Wdec transpose f32->bf16 (BW-bound, linear).
// 35 KB LDS union -> 4 blocks/CU (2 enc + 2 trans resident; in-order dispatch
// places encoder blocks first). Transpose soaks the encoder's idle bandwidth
// instead of serializing after it.
__global__ __launch_bounds__(256, 4) void k_enc_trans(
    const unsigned short* __restrict__ xcp,
    const float* __restrict__ Wenc,
    const float* __restrict__ benc,
    unsigned short* __restrict__ preb,
    const float* __restrict__ Wdec,
    unsigned short* __restrict__ wt) {
  __shared__ __align__(16) char smem[35072];   // max(32768 enc, 35072 trans)
  const int tid = threadIdx.x;

  if (blockIdx.x >= 512) {               // ---------- transpose role ----------
    unsigned short* tile = (unsigned short*)smem;   // [128][137]
    const int tb = blockIdx.x - 512;     // 0..3071
    const int h0 = (tb & 63) * 128;
    const int rem = tb >> 6;
    const int d0 = (rem % 6) * 128;
    const int t  = rem / 6;
    const float* src = Wdec + ((size_t)t * DIN + d0) * DSAE + h0;
#pragma unroll
    for (int i = 0; i < 16; ++i) {
      const int F = (i * 256 + tid) * 4;
      const int r = F >> 7, c = F & 127;
      float4 v = *(const float4*)(src + (size_t)r * DSAE + c);
      unsigned short* p = &tile[r * 137 + c];
      p[0] = (unsigned short)rne1(v.x); p[1] = (unsigned short)rne1(v.y);
      p[2] = (unsigned short)rne1(v.z); p[3] = (unsigned short)rne1(v.w);
    }
    __syncthreads();
#pragma unroll
    for (int j = 0; j < 16; ++j) {
      const int E  = j * 256 + tid;
      const int hr = E >> 5;
      const int dc = (E & 31) * 4;
      unsigned a = (unsigned)tile[(dc + 0) * 137 + hr] |
                   ((unsigned)tile[(dc + 1) * 137 + hr] << 16);
      unsigned b = (unsigned)tile[(dc + 2) * 137 + hr] |
                   ((unsigned)tile[(dc + 3) * 137 + hr] << 16);
      uint2 o; o.x = a; o.y = b;
      *(uint2*)(wt + ((size_t)(t * DSAE + h0 + hr)) * DIN + d0 + dc) = o;
    }
    return;
  }

  // ------------------------------ encoder role -------------------------------
  float* Bs = (float*)smem;              // 4 x 8 KB fp32 quad-buffer
  const int wm = tid >> 6, lane = tid & 63;
  const int l15 = lane & 15, kc = lane >> 4;

  int gRow[2], gCol[2], ldsL[2];
#pragma unroll
  for (int i = 0; i < 2; ++i) {
    int L = i * 4096 + tid * 16;
    int G = L ^ (((L >> 7) & 7) << 4);
    gRow[i] = G >> 7;
    gCol[i] = (G & 127) >> 2;
    ldsL[i] = L;
  }
  int bOff0[4], bOff1[4];
#pragma unroll
  for (int ni = 0; ni < 4; ++ni) {
    int row = ni * 16 + l15;
    int P = row * 128 + kc * 32;
    int sw = (row & 7) << 4;
    bOff0[ni] = P ^ sw;
    bOff1[ni] = (P + 16) ^ sw;
  }
  constexpr size_t A_MI = (size_t)T_SZ * NSK * 512;   // +16 b-rows (halfwords)

  for (int tile = 0; tile < 2; ++tile) {
    const int tileId = blockIdx.x + tile * 512;      // 0..1023
    const int t  = tileId >> 7;
    const int n0 = (tileId & 127) * 64;

    const float* bG = Wenc + ((size_t)t * DSAE + n0) * DIN;
    const unsigned short* aP =
        xcp + ((size_t)(wm * 4 * T_SZ + t) * NSK) * 512 + lane * 8;

    auto STAGE = [&](int buf, int s) {
#pragma unroll
      for (int i = 0; i < 2; ++i)
        gload_lds16(bG + (size_t)gRow[i] * DIN + s * 32 + gCol[i],
                    (char*)Bs + buf * 8192 + ldsL[i]);
    };

    f32x4 acc[4][4] = {};
    bf16x8 aA[4], aB[4];
    STAGE(0, 0);
#pragma unroll
    for (int mi = 0; mi < 4; ++mi)
      aA[mi] = *(const bf16x8*)(aP + mi * A_MI);
    STAGE(1, 1);

#define ENC_W6 asm volatile("s_waitcnt vmcnt(6)" ::: "memory")
#define ENC_W4 asm volatile("s_waitcnt vmcnt(4)" ::: "memory")
#define ENC_W0 asm volatile("s_waitcnt vmcnt(0)" ::: "memory")
#define ENC_STEP(u, PFB, PFA, WAITOP) do {                                   \
    if (PFB) STAGE(((u) + 2) & 3, s0 + (u) + 2);                             \
    if (PFA) {                                                               \
      const unsigned short* ap = aP + (size_t)(s0 + (u) + 1) * 512;          \
      _Pragma("unroll")                                                      \
      for (int mi = 0; mi < 4; ++mi) {                                       \
        bf16x8 v = *(const bf16x8*)(ap + mi * A_MI);                         \
        if ((u) % 2 == 0) aB[mi] = v; else aA[mi] = v;                       \
      }                                                                      \
    }                                                                        \
    __builtin_amdgcn_sched_barrier(0);                                       \
    WAITOP;                                                                  \
    __builtin_amdgcn_s_barrier();                                            \
    __builtin_amdgcn_sched_barrier(0);                                       \
    {                                                                        \
      const char* bb = (const char*)Bs + ((u) & 3) * 8192;                   \
      _Pragma("unroll")                                                      \
      for (int ni = 0; ni < 4; ++ni) {                                       \
        f32x4 f0 = *(const f32x4*)(bb + bOff0[ni]);                          \
        f32x4 f1 = *(const f32x4*)(bb + bOff1[ni]);                          \
        union { uint32_t w[4]; bf16x8 h; } cvu;                              \
        cvu.w[0] = packtr(f0.x, f0.y); cvu.w[1] = packtr(f0.z, f0.w);        \
        cvu.w[2] = packtr(f1.x, f1.y); cvu.w[3] = packtr(f1.z, f1.w);        \
        _Pragma("unroll")                                                    \
        for (int mi = 0; mi < 4; ++mi)                                       \
          acc[mi][ni] = __builtin_amdgcn_mfma_f32_16x16x32_bf16(             \
              ((u) % 2 == 0) ? aA[mi] : aB[mi], cvu.h, acc[mi][ni], 0, 0, 0);\
      }                                                                      \
    }                                                                        \
  } while (0)

    int s0 = 0;
    for (int g = 0; g < 5; ++g, s0 += 4) {
      ENC_STEP(0, true, true, ENC_W6); ENC_STEP(1, true, true, ENC_W6);
      ENC_STEP(2, true, true, ENC_W6); ENC_STEP(3, true, true, ENC_W6);
    }
    ENC_STEP(0, true, true, ENC_W6);  ENC_STEP(1, true, true, ENC_W6);
    ENC_STEP(2, false, true, ENC_W4); ENC_STEP(3, false, false, ENC_W0);
#undef ENC_STEP
#undef ENC_W6
#undef ENC_W4
#undef ENC_W0

    // epilogue: C/D layout col=lane&15, row=(lane>>4)*4+reg; bf16 stores
#pragma unroll
    for (int ni = 0; ni < 4; ++ni) {
      const int col = n0 + ni * 16 + l15;
      const float bias = benc[(size_t)t * DSAE + col];
#pragma unroll
      for (int mi = 0; mi < 4; ++mi) {
        const int rbase = wm * 64 + mi * 16 + kc * 4;
#pragma unroll
        for (int j = 0; j < 4; ++j)
          preb[((size_t)(rbase + j) * T_SZ + t) * DSAE + col] =
              (unsigned short)rne1(acc[mi][ni][j] + bias);
      }
    }
    if (tile == 0) __syncthreads();   // tile boundary: full drain + barrier
  }
}

// ---------------- fused top-k select + sparse decode + loss ------------------
// Block r: select (bf16 pre row -> threshold -> sort -> fp64-refined boundary)
// keeps the sel list in LDS and immediately decodes x_hat row r from wt
// (TRANSPOSED) or raw Wdec (fallback). u is scatter-only (pre-zeroed).
template <bool TRANSPOSED>
__global__ __launch_bounds__(256) void k_select_dec(
    const float* __restrict__ xc,
    const float* __restrict__ Wenc,
    const float* __restrict__ benc,
    const unsigned short* __restrict__ preb,
    const void* __restrict__ Wd_,
    const float* __restrict__ x,
    const float* __restrict__ bdec,
    float* __restrict__ u,
    float* __restrict__ xhat,
    float* __restrict__ loss) {
  const int r = blockIdx.x, t = r & (T_SZ - 1);
  __shared__ float sp[DSAE];     // 32 KB
  __shared__ float redf[4], redf2[4];
  __shared__ int   redi[4];
  __shared__ float cv[CAND_CAP]; __shared__ int ci[CAND_CAP];
  __shared__ float sv[CAND_CAP]; __shared__ int si[CAND_CAP];
  __shared__ float rv[RCAP];     __shared__ int ri[RCAP];
  __shared__ double rd[RCAP];
  __shared__ double xd[DIN];     // 6 KB
  __shared__ int   dsi[KSEL];    // final selection (decoder input)
  __shared__ float dsv[KSEL];
  __shared__ float rbuf[4];
  __shared__ int   s_n, s_nR, s_A, s_nW;
  const int tid = threadIdx.x, lane = tid & 63, w = tid >> 6;

  // load bf16 row, convert, moments
  float s1 = 0.f, s2 = 0.f;
#pragma unroll
  for (int sgm = 0; sgm < 4; ++sgm) {
    const int i0 = sgm * 2048 + tid * 8;
    uint4 pk = *(const uint4*)(preb + (size_t)r * DSAE + i0);
    const unsigned wds[4] = {pk.x, pk.y, pk.z, pk.w};
#pragma unroll
    for (int q = 0; q < 4; ++q) {
      float lo = __uint_as_float(wds[q] << 16);
      float hi = __uint_as_float(wds[q] & 0xFFFF0000u);
      sp[i0 + q * 2 + 0] = lo;
      sp[i0 + q * 2 + 1] = hi;
      s1 += lo + hi; s2 = fmaf(lo, lo, fmaf(hi, hi, s2));
    }
  }
  for (int off = 32; off; off >>= 1) {
    s1 += __shfl_down(s1, off); s2 += __shfl_down(s2, off);
  }
  if (lane == 0) { redf[w] = s1; redf2[w] = s2; }
  __syncthreads();
  const float mean = (redf[0] + redf[1] + redf[2] + redf[3]) * (1.f / DSAE);
  const float var  = (redf2[0] + redf2[1] + redf2[2] + redf2[3]) * (1.f / DSAE) - mean * mean;
  const float sd   = sqrtf(fmaxf(var, 1e-20f));

  auto countGE = [&](float th) -> int {
    int c = 0;
#pragma unroll
    for (int sgm = 0; sgm < DSAE / 256; ++sgm)
      c += (sp[tid + sgm * 256] >= th) ? 1 : 0;
    for (int off = 32; off; off >>= 1) c += __shfl_down(c, off);
    __syncthreads();
    if (lane == 0) redi[w] = c;
    __syncthreads();
    return redi[0] + redi[1] + redi[2] + redi[3];
  };

  float tlo = mean + 2.0f * sd, thi = mean + 3.5f * sd;
  for (int it = 0; it < 8 && countGE(tlo) < KSEL; ++it) tlo -= sd;
  float th = mean + 2.52f * sd;
  int c = countGE(th);
  for (int it = 0; it < 24 && (c < KSEL || c > CAND_CAP); ++it) {
    if (c > CAND_CAP) tlo = th; else thi = th;
    th = 0.5f * (tlo + thi);
    c = countGE(th);
  }
  if (c < KSEL) { th = tlo; c = countGE(th); }

  if (tid == 0) s_n = 0;
  __syncthreads();
  for (int sgm = 0; sgm < DSAE / 256; ++sgm) {
    int i = tid + sgm * 256;
    float v = sp[i];
    if (v >= th) {
      int p = atomicAdd(&s_n, 1);
      if (p < CAND_CAP) { cv[p] = v; ci[p] = i; }
    }
  }
  __syncthreads();
  const int n = s_n < CAND_CAP ? s_n : CAND_CAP;

  if (tid < n) {
    float v = cv[tid]; int id = ci[tid];
    int rk = 0;
    for (int j = 0; j < n; ++j) {
      float vj = cv[j];
      rk += (vj > v || (vj == v && ci[j] < id)) ? 1 : 0;
    }
    sv[rk] = v; si[rk] = id;
  }
  __syncthreads();

  const float v32 = sv[KSEL - 1];
  const float wlo = v32 - EPS_W, whi = v32 + EPS_W;
  if (tid == 0) {
    int A = 0;
    while (A < KSEL - 1 && sv[A] > whi) ++A;
    s_A = A;
    int e = A;
    while (e < n && sv[e] >= wlo) ++e;
    s_nW = e - A;
  }
  __syncthreads();
  const int A  = s_A;
  const int nW = s_nW < RCAP ? s_nW : RCAP;
  if (tid < nW) { rv[tid] = sv[A + tid]; ri[tid] = si[A + tid]; }
  if (tid == 0) s_nR = nW;
  __syncthreads();
  if (th > wlo) {
    for (int sgm = 0; sgm < DSAE / 256; ++sgm) {
      int i = tid + sgm * 256;
      float v = sp[i];
      if (v >= wlo && v < th) {
        int p = atomicAdd(&s_nR, 1);
        if (p < RCAP) { rv[p] = v; ri[p] = i; }
      }
    }
  }
  __syncthreads();
  const int nR = s_nR < RCAP ? s_nR : RCAP;

  // fp64 refinement of boundary members
  if (nR >= 2) {
    for (int i = tid; i < DIN; i += 256) xd[i] = (double)xc[(size_t)r * DIN + i];
    __syncthreads();
    for (int j = w; j < nR; j += 4) {
      const int h = ri[j];
      const float* wrow = Wenc + ((size_t)t * DSAE + h) * DIN;
      double s = 0.0;
#pragma unroll
      for (int ss = 0; ss < DIN / 64; ++ss)
        s += xd[lane + 64 * ss] * (double)wrow[lane + 64 * ss];
      for (int off = 32; off; off >>= 1) s += __shfl_down(s, off);
      if (lane == 0) rd[j] = s + (double)benc[(size_t)t * DSAE + h];
    }
  } else if (nR == 1) {
    if (tid == 0) rd[0] = (double)rv[0];
  }
  __syncthreads();

  // final selection -> LDS (dsi/dsv) + scatter u (u pre-zeroed by k_init)
  float* urow = u + (size_t)r * DSAE;
  if (tid < A) {
    float val = fmaxf(sv[tid], 0.f);
    urow[si[tid]] = val;
    dsi[tid] = si[tid]; dsv[tid] = val;
  }
  const int need = KSEL - A;
  if (tid < nR) {
    double v = rd[tid]; int id = ri[tid];
    int rk = 0;
    for (int j = 0; j < nR; ++j) {
      double vj = rd[j];
      rk += (vj > v || (vj == v && ri[j] < id)) ? 1 : 0;
    }
    if (rk < need) {
      float val = fmaxf((float)v, 0.f);
      urow[id] = val;
      dsi[A + rk] = id; dsv[A + rk] = val;
    }
  }
  __syncthreads();

  // ---------------- decode x_hat row r + fused loss --------------------------
  float acc[3];
#pragma unroll
  for (int i = 0; i < 3; ++i) acc[i] = bdec[(size_t)t * DIN + tid + 256 * i];
#pragma unroll 4
  for (int j = 0; j < KSEL; ++j) {
    const int h = dsi[j] & (DSAE - 1);
    const float v = dsv[j];
    if (TRANSPOSED) {
      const unsigned short* wrow =
          (const unsigned short*)Wd_ + ((size_t)t * DSAE + h) * DIN;
#pragma unroll
      for (int i = 0; i < 3; ++i)
        acc[i] = fmaf(v, bf16tof(wrow[tid + 256 * i]), acc[i]);
    } else {
      const float* Wd = (const float*)Wd_;
#pragma unroll
      for (int i = 0; i < 3; ++i)
        acc[i] = fmaf(v, Wd[((size_t)t * DIN + tid + 256 * i) * DSAE + h], acc[i]);
    }
  }
  float sq = 0.f;
#pragma unroll
  for (int i = 0; i < 3; ++i) {
    const int d = tid + 256 * i;
    const float xv = x[(size_t)r * DIN + d];
    xhat[(size_t)r * DIN + d] = acc[i];
    const float e = acc[i] - xv;
    sq = fmaf(e, e, sq);
  }
  for (int off = 32; off; off >>= 1) sq += __shfl_down(sq, off);
  if ((tid & 63) == 0) rbuf[tid >> 6] = sq;
  __syncthreads();
  if (tid == 0)
    atomicAdd(loss, (rbuf[0] + rbuf[1] + rbuf[2] + rbuf[3]) * (1.0f / NROWS));
}

// ---------------- host ------------------------------------------------------
extern "C" void kernel_launch(void* const* d_in, const int* in_sizes, int n_in,
                              void* d_out, int out_size, void* d_ws, size_t ws_size,
                              hipStream_t stream) {
  const float* x    = (const float*)d_in[0];
  const float* Wenc = (const float*)d_in[1];
  const float* benc = (const float*)d_in[2];
  const float* Wdec = (const float*)d_in[3];
  const float* bdec = (const float*)d_in[4];

  float* out  = (float*)d_out;
  float* loss = out;
  float* xhat = out + 1;
  float* u    = out + 1 + (size_t)NROWS * DIN;  // (B,T,DSAE) == rows r

  float*          wsf  = (float*)d_ws;
  float*          xc   = wsf + OFF_XC;
  unsigned short* xcp  = (unsigned short*)(wsf + OFF_XCP);
  unsigned short* preb = (unsigned short*)(wsf + OFF_PREB);
  unsigned short* big  = (unsigned short*)(wsf + OFF_BIG);  // wt (bf16)
  const bool fast = ws_size >= WS_FAST_WORDS * sizeof(float);

  k_init<<<2816, 256, 0, stream>>>(x, bdec, xc, xcp, u, loss);
  if (fast) {
    k_enc_trans<<<512 + 3072, 256, 0, stream>>>(xcp, Wenc, benc, preb, Wdec, big);
    k_select_dec<true><<<NROWS, 256, 0, stream>>>(xc, Wenc, benc, preb, big,
                                                  x, bdec, u, xhat, loss);
  } else {
    k_enc_trans<<<512, 256, 0, stream>>>(xcp, Wenc, benc, preb, Wdec, big);
    k_select_dec<false><<<NROWS, 256, 0, stream>>>(xc, Wenc, benc, preb, Wdec,
                                                   x, bdec, u, xhat, loss);
  }
}

// Round 21
// 212.019 us; speedup vs baseline: 1.5961x; 1.5961x over previous
//
#include <hip/hip_runtime.h>
#include <cstdint>
#include <cstddef>

// ---------------- problem constants (fixed by setup_inputs; k==32 always) ----
constexpr int B_SZ  = 256;
constexpr int T_SZ  = 8;
constexpr int DIN   = 768;
constexpr int DSAE  = 8192;
constexpr int KSEL  = 32;
constexpr int NROWS = B_SZ * T_SZ;        // 2048 (row r = b*T + t)
constexpr int CAND_CAP = 64;
constexpr int RCAP  = 32;                 // boundary-window capacity
constexpr float EPS_W = 5.5e-4f;          // covers dot-err + bf16-pre quant
constexpr int NSK   = DIN / 32;           // 24 K-steps

// ---------------- workspace layout (units: 4-byte words) ---------------------
constexpr size_t XC_SZ    = (size_t)NROWS * DIN;            // 1,572,864 w
constexpr size_t OFF_XC   = 0;
constexpr size_t OFF_XCP  = OFF_XC + XC_SZ;                 // packed bf16 xc
constexpr size_t XCP_W    = XC_SZ / 2;
constexpr size_t OFF_PREB = OFF_XCP + XCP_W;                // bf16 pre scratch
constexpr size_t PREB_W   = (size_t)NROWS * DSAE / 2;       // 8,388,608 w (32 MB)
constexpr size_t OFF_BIG  = OFF_PREB + PREB_W;
constexpr size_t BIG_W    = (size_t)T_SZ * DSAE * DIN / 2;  // 25,165,824 w
constexpr size_t WS_FAST_WORDS = OFF_BIG + BIG_W;           // ~144 MB

typedef short bf16x8 __attribute__((ext_vector_type(8)));  // 8 bf16 = 4 VGPR
typedef float f32x4  __attribute__((ext_vector_type(4)));

__device__ inline unsigned rne1(float x) {
  unsigned u = __float_as_uint(x);
  return (u + 0x7FFFu + ((u >> 16) & 1u)) >> 16;
}
__device__ inline float bf16tof(unsigned short v) {
  return __uint_as_float((unsigned)v << 16);
}
__device__ inline unsigned packtr(float a, float b) {
  return (__float_as_uint(a) >> 16) | (__float_as_uint(b) & 0xFFFF0000u);
}
__device__ inline void gload_lds16(const void* g, void* l) {
  __builtin_amdgcn_global_load_lds(
      (const __attribute__((address_space(1))) void*)g,
      (__attribute__((address_space(3))) void*)l, 16, 0, 0);
}

// ---------------- k_init: u-zero + loss-zero + xc/xcp (role by blockIdx) -----
// Homogeneous resource profile (no LDS, low VGPR) -> safe role fusion.
// blocks [0,2048): zero the u region (linear float4 fill).
// blocks [2048,2816): xc = x - b_dec; xcp = fragment-packed bf16(xc).
__global__ __launch_bounds__(256) void k_init(const float* __restrict__ x,
                                              const float* __restrict__ bdec,
                                              float* __restrict__ xc,
                                              unsigned short* __restrict__ xcp,
                                              float* __restrict__ u,
                                              float* __restrict__ loss) {
  const int tid = threadIdx.x;
  if (blockIdx.x < 2048) {
    if (blockIdx.x == 0 && tid == 0) *loss = 0.f;
    const size_t base = (size_t)(blockIdx.x * 256 + tid) * 4;
    const size_t stride = (size_t)2048 * 256 * 4;
    const float4 z = {0.f, 0.f, 0.f, 0.f};
    for (size_t i = base; i < (size_t)NROWS * DSAE; i += stride)
      *(float4*)(u + i) = z;
    return;
  }
  const int c = (blockIdx.x - 2048) * 256 + tid;  // 0 .. 196607
  const int lane = c & 63;
  const int uu = c >> 6;
  const int s  = uu % NSK;
  const int tt = (uu / NSK) & (T_SZ - 1);
  const int gm = uu / (NSK * T_SZ);               // 0..15
  const int b  = gm * 16 + (lane & 15);
  const int k0 = s * 32 + (lane >> 4) * 8;
  const size_t rowOff = ((size_t)(b * T_SZ + tt)) * DIN + k0;
  float4 v0 = *(const float4*)(x + rowOff);
  float4 v1 = *(const float4*)(x + rowOff + 4);
  float4 d0 = *(const float4*)(bdec + tt * DIN + k0);
  float4 d1 = *(const float4*)(bdec + tt * DIN + k0 + 4);
  v0.x -= d0.x; v0.y -= d0.y; v0.z -= d0.z; v0.w -= d0.w;
  v1.x -= d1.x; v1.y -= d1.y; v1.z -= d1.z; v1.w -= d1.w;
  *(float4*)(xc + rowOff) = v0;
  *(float4*)(xc + rowOff + 4) = v1;
  uint4 p;
  p.x = rne1(v0.x) | (rne1(v0.y) << 16);
  p.y = rne1(v0.z) | (rne1(v0.w) << 16);
  p.z = rne1(v1.x) | (rne1(v1.y) << 16);
  p.w = rne1(v1.z) | (rne1(v1.w) << 16);
  *(uint4*)(xcp + (size_t)c * 8) = p;
}

// ---------------- encoder: pre = xc @ W_enc[t]^T + b_enc (bf16 MFMA) ---------
// r19 standalone (own tuned config: 96 VGPR, 2 blocks/CU). bf16 pre output.
__global__ __launch_bounds__(256, 2) void k_encoder(const unsigned short* __restrict__ xcp,
                                                    const float* __restrict__ Wenc,
                                                    const float* __restrict__ benc,
                                                    unsigned short* __restrict__ preb) {
  __shared__ __align__(16) float Bs[4][64 * 32];   // 4 x 8 KB fp32
  const int tid = threadIdx.x;
  const int wm = tid >> 6, lane = tid & 63;
  const int l15 = lane & 15, kc = lane >> 4;

  int gRow[2], gCol[2], ldsL[2];
#pragma unroll
  for (int i = 0; i < 2; ++i) {
    int L = i * 4096 + tid * 16;
    int G = L ^ (((L >> 7) & 7) << 4);
    gRow[i] = G >> 7;
    gCol[i] = (G & 127) >> 2;
    ldsL[i] = L;
  }
  int bOff0[4], bOff1[4];
#pragma unroll
  for (int ni = 0; ni < 4; ++ni) {
    int row = ni * 16 + l15;
    int P = row * 128 + kc * 32;
    int sw = (row & 7) << 4;
    bOff0[ni] = P ^ sw;
    bOff1[ni] = (P + 16) ^ sw;
  }
  constexpr size_t A_MI = (size_t)T_SZ * NSK * 512;   // +16 b-rows (halfwords)

  for (int tile = 0; tile < 2; ++tile) {
    const int tileId = blockIdx.x + tile * 512;      // 0..1023
    const int t  = tileId >> 7;
    const int n0 = (tileId & 127) * 64;

    const float* bG = Wenc + ((size_t)t * DSAE + n0) * DIN;
    const unsigned short* aP =
        xcp + ((size_t)(wm * 4 * T_SZ + t) * NSK) * 512 + lane * 8;

    auto STAGE = [&](int buf, int s) {
#pragma unroll
      for (int i = 0; i < 2; ++i)
        gload_lds16(bG + (size_t)gRow[i] * DIN + s * 32 + gCol[i],
                    (char*)&Bs[0][0] + buf * 8192 + ldsL[i]);
    };

    f32x4 acc[4][4] = {};
    bf16x8 aA[4], aB[4];
    STAGE(0, 0);
#pragma unroll
    for (int mi = 0; mi < 4; ++mi)
      aA[mi] = *(const bf16x8*)(aP + mi * A_MI);
    STAGE(1, 1);

#define ENC_W6 asm volatile("s_waitcnt vmcnt(6)" ::: "memory")
#define ENC_W4 asm volatile("s_waitcnt vmcnt(4)" ::: "memory")
#define ENC_W0 asm volatile("s_waitcnt vmcnt(0)" ::: "memory")
#define ENC_STEP(u, PFB, PFA, WAITOP) do {                                   \
    if (PFB) STAGE(((u) + 2) & 3, s0 + (u) + 2);                             \
    if (PFA) {                                                               \
      const unsigned short* ap = aP + (size_t)(s0 + (u) + 1) * 512;          \
      _Pragma("unroll")                                                      \
      for (int mi = 0; mi < 4; ++mi) {                                       \
        bf16x8 v = *(const bf16x8*)(ap + mi * A_MI);                         \
        if ((u) % 2 == 0) aB[mi] = v; else aA[mi] = v;                       \
      }                                                                      \
    }                                                                        \
    __builtin_amdgcn_sched_barrier(0);                                       \
    WAITOP;                                                                  \
    __builtin_amdgcn_s_barrier();                                            \
    __builtin_amdgcn_sched_barrier(0);                                       \
    {                                                                        \
      const char* bb = (const char*)&Bs[0][0] + ((u) & 3) * 8192;            \
      _Pragma("unroll")                                                      \
      for (int ni = 0; ni < 4; ++ni) {                                       \
        f32x4 f0 = *(const f32x4*)(bb + bOff0[ni]);                          \
        f32x4 f1 = *(const f32x4*)(bb + bOff1[ni]);                          \
        union { uint32_t w[4]; bf16x8 h; } cvu;                              \
        cvu.w[0] = packtr(f0.x, f0.y); cvu.w[1] = packtr(f0.z, f0.w);        \
        cvu.w[2] = packtr(f1.x, f1.y); cvu.w[3] = packtr(f1.z, f1.w);        \
        _Pragma("unroll")                                                    \
        for (int mi = 0; mi < 4; ++mi)                                       \
          acc[mi][ni] = __builtin_amdgcn_mfma_f32_16x16x32_bf16(             \
              ((u) % 2 == 0) ? aA[mi] : aB[mi], cvu.h, acc[mi][ni], 0, 0, 0);\
      }                                                                      \
    }                                                                        \
  } while (0)

    int s0 = 0;
    for (int g = 0; g < 5; ++g, s0 += 4) {
      ENC_STEP(0, true, true, ENC_W6); ENC_STEP(1, true, true, ENC_W6);
      ENC_STEP(2, true, true, ENC_W6); ENC_STEP(3, true, true, ENC_W6);
    }
    ENC_STEP(0, true, true, ENC_W6);  ENC_STEP(1, true, true, ENC_W6);
    ENC_STEP(2, false, true, ENC_W4); ENC_STEP(3, false, false, ENC_W0);
#undef ENC_STEP
#undef ENC_W6
#undef ENC_W4
#undef ENC_W0

    // epilogue: C/D layout col=lane&15, row=(lane>>4)*4+reg; bf16 stores
#pragma unroll
    for (int ni = 0; ni < 4; ++ni) {
      const int col = n0 + ni * 16 + l15;
      const float bias = benc[(size_t)t * DSAE + col];
#pragma unroll
      for (int mi = 0; mi < 4; ++mi) {
        const int rbase = wm * 64 + mi * 16 + kc * 4;
#pragma unroll
        for (int j = 0; j < 4; ++j)
          preb[((size_t)(rbase + j) * T_SZ + t) * DSAE + col] =
              (unsigned short)rne1(acc[mi][ni][j] + bias);
      }
    }
    if (tile == 0) __syncthreads();   // tile boundary: full drain + barrier
  }
}

// ---------------- W_dec transpose: 128x128 tiles, f32 -> bf16 ----------------
__global__ __launch_bounds__(256) void k_transpose(const float* __restrict__ W,
                                                   unsigned short* __restrict__ Wt) {
  __shared__ unsigned short tile[128 * 137];   // 34.25 KB
  const int h0 = blockIdx.x * 128;
  const int d0 = blockIdx.y * 128;
  const int t  = blockIdx.z;
  const int tid = threadIdx.x;
  const float* src = W + ((size_t)t * DIN + d0) * DSAE + h0;
#pragma unroll
  for (int i = 0; i < 16; ++i) {
    const int F = (i * 256 + tid) * 4;
    const int r = F >> 7, c = F & 127;
    float4 v = *(const float4*)(src + (size_t)r * DSAE + c);
    unsigned short* p = &tile[r * 137 + c];
    p[0] = (unsigned short)rne1(v.x); p[1] = (unsigned short)rne1(v.y);
    p[2] = (unsigned short)rne1(v.z); p[3] = (unsigned short)rne1(v.w);
  }
  __syncthreads();
#pragma unroll
  for (int j = 0; j < 16; ++j) {
    const int E  = j * 256 + tid;
    const int hr = E >> 5;
    const int dc = (E & 31) * 4;
    unsigned a = (unsigned)tile[(dc + 0) * 137 + hr] |
                 ((unsigned)tile[(dc + 1) * 137 + hr] << 16);
    unsigned b = (unsigned)tile[(dc + 2) * 137 + hr] |
                 ((unsigned)tile[(dc + 3) * 137 + hr] << 16);
    uint2 o; o.x = a; o.y = b;
    *(uint2*)(Wt + ((size_t)(t * DSAE + h0 + hr)) * DIN + d0 + dc) = o;
  }
}

// ---------------- fused top-k select + sparse decode + loss ------------------
// Block r: select (bf16 pre row -> threshold -> sort -> fp64-refined boundary)
// keeps the sel list in LDS and immediately decodes x_hat row r.
template <bool TRANSPOSED>
__global__ __launch_bounds__(256) void k_select_dec(
    const float* __restrict__ xc,
    const float* __restrict__ Wenc,
    const float* __restrict__ benc,
    const unsigned short* __restrict__ preb,
    const void* __restrict__ Wd_,
    const float* __restrict__ x,
    const float* __restrict__ bdec,
    float* __restrict__ u,
    float* __restrict__ xhat,
    float* __restrict__ loss) {
  const int r = blockIdx.x, t = r & (T_SZ - 1);
  __shared__ float sp[DSAE];     // 32 KB
  __shared__ float redf[4], redf2[4];
  __shared__ int   redi[4];
  __shared__ float cv[CAND_CAP]; __shared__ int ci[CAND_CAP];
  __shared__ float sv[CAND_CAP]; __shared__ int si[CAND_CAP];
  __shared__ float rv[RCAP];     __shared__ int ri[RCAP];
  __shared__ double rd[RCAP];
  __shared__ double xd[DIN];     // 6 KB
  __shared__ int   dsi[KSEL];    // final selection (decoder input)
  __shared__ float dsv[KSEL];
  __shared__ float rbuf[4];
  __shared__ int   s_n, s_nR, s_A, s_nW;
  const int tid = threadIdx.x, lane = tid & 63, w = tid >> 6;

  // load bf16 row, convert, moments
  float s1 = 0.f, s2 = 0.f;
#pragma unroll
  for (int sgm = 0; sgm < 4; ++sgm) {
    const int i0 = sgm * 2048 + tid * 8;
    uint4 pk = *(const uint4*)(preb + (size_t)r * DSAE + i0);
    const unsigned wds[4] = {pk.x, pk.y, pk.z, pk.w};
#pragma unroll
    for (int q = 0; q < 4; ++q) {
      float lo = __uint_as_float(wds[q] << 16);
      float hi = __uint_as_float(wds[q] & 0xFFFF0000u);
      sp[i0 + q * 2 + 0] = lo;
      sp[i0 + q * 2 + 1] = hi;
      s1 += lo + hi; s2 = fmaf(lo, lo, fmaf(hi, hi, s2));
    }
  }
  for (int off = 32; off; off >>= 1) {
    s1 += __shfl_down(s1, off); s2 += __shfl_down(s2, off);
  }
  if (lane == 0) { redf[w] = s1; redf2[w] = s2; }
  __syncthreads();
  const float mean = (redf[0] + redf[1] + redf[2] + redf[3]) * (1.f / DSAE);
  const float var  = (redf2[0] + redf2[1] + redf2[2] + redf2[3]) * (1.f / DSAE) - mean * mean;
  const float sd   = sqrtf(fmaxf(var, 1e-20f));

  auto countGE = [&](float th) -> int {
    int c = 0;
#pragma unroll
    for (int sgm = 0; sgm < DSAE / 256; ++sgm)
      c += (sp[tid + sgm * 256] >= th) ? 1 : 0;
    for (int off = 32; off; off >>= 1) c += __shfl_down(c, off);
    __syncthreads();
    if (lane == 0) redi[w] = c;
    __syncthreads();
    return redi[0] + redi[1] + redi[2] + redi[3];
  };

  float tlo = mean + 2.0f * sd, thi = mean + 3.5f * sd;
  for (int it = 0; it < 8 && countGE(tlo) < KSEL; ++it) tlo -= sd;
  float th = mean + 2.52f * sd;
  int c = countGE(th);
  for (int it = 0; it < 24 && (c < KSEL || c > CAND_CAP); ++it) {
    if (c > CAND_CAP) tlo = th; else thi = th;
    th = 0.5f * (tlo + thi);
    c = countGE(th);
  }
  if (c < KSEL) { th = tlo; c = countGE(th); }

  if (tid == 0) s_n = 0;
  __syncthreads();
  for (int sgm = 0; sgm < DSAE / 256; ++sgm) {
    int i = tid + sgm * 256;
    float v = sp[i];
    if (v >= th) {
      int p = atomicAdd(&s_n, 1);
      if (p < CAND_CAP) { cv[p] = v; ci[p] = i; }
    }
  }
  __syncthreads();
  const int n = s_n < CAND_CAP ? s_n : CAND_CAP;

  if (tid < n) {
    float v = cv[tid]; int id = ci[tid];
    int rk = 0;
    for (int j = 0; j < n; ++j) {
      float vj = cv[j];
      rk += (vj > v || (vj == v && ci[j] < id)) ? 1 : 0;
    }
    sv[rk] = v; si[rk] = id;
  }
  __syncthreads();

  const float v32 = sv[KSEL - 1];
  const float wlo = v32 - EPS_W, whi = v32 + EPS_W;
  if (tid == 0) {
    int A = 0;
    while (A < KSEL - 1 && sv[A] > whi) ++A;
    s_A = A;
    int e = A;
    while (e < n && sv[e] >= wlo) ++e;
    s_nW = e - A;
  }
  __syncthreads();
  const int A  = s_A;
  const int nW = s_nW < RCAP ? s_nW : RCAP;
  if (tid < nW) { rv[tid] = sv[A + tid]; ri[tid] = si[A + tid]; }
  if (tid == 0) s_nR = nW;
  __syncthreads();
  if (th > wlo) {
    for (int sgm = 0; sgm < DSAE / 256; ++sgm) {
      int i = tid + sgm * 256;
      float v = sp[i];
      if (v >= wlo && v < th) {
        int p = atomicAdd(&s_nR, 1);
        if (p < RCAP) { rv[p] = v; ri[p] = i; }
      }
    }
  }
  __syncthreads();
  const int nR = s_nR < RCAP ? s_nR : RCAP;

  // fp64 refinement of boundary members
  if (nR >= 2) {
    for (int i = tid; i < DIN; i += 256) xd[i] = (double)xc[(size_t)r * DIN + i];
    __syncthreads();
    for (int j = w; j < nR; j += 4) {
      const int h = ri[j];
      const float* wrow = Wenc + ((size_t)t * DSAE + h) * DIN;
      double s = 0.0;
#pragma unroll
      for (int ss = 0; ss < DIN / 64; ++ss)
        s += xd[lane + 64 * ss] * (double)wrow[lane + 64 * ss];
      for (int off = 32; off; off >>= 1) s += __shfl_down(s, off);
      if (lane == 0) rd[j] = s + (double)benc[(size_t)t * DSAE + h];
    }
  } else if (nR == 1) {
    if (tid == 0) rd[0] = (double)rv[0];
  }
  __syncthreads();

  // final selection -> LDS (dsi/dsv) + scatter u (u pre-zeroed by k_init)
  float* urow = u + (size_t)r * DSAE;
  if (tid < A) {
    float val = fmaxf(sv[tid], 0.f);
    urow[si[tid]] = val;
    dsi[tid] = si[tid]; dsv[tid] = val;
  }
  const int need = KSEL - A;
  if (tid < nR) {
    double v = rd[tid]; int id = ri[tid];
    int rk = 0;
    for (int j = 0; j < nR; ++j) {
      double vj = rd[j];
      rk += (vj > v || (vj == v && ri[j] < id)) ? 1 : 0;
    }
    if (rk < need) {
      float val = fmaxf((float)v, 0.f);
      urow[id] = val;
      dsi[A + rk] = id; dsv[A + rk] = val;
    }
  }
  __syncthreads();

  // ---------------- decode x_hat row r + fused loss --------------------------
  float acc[3];
#pragma unroll
  for (int i = 0; i < 3; ++i) acc[i] = bdec[(size_t)t * DIN + tid + 256 * i];
#pragma unroll 4
  for (int j = 0; j < KSEL; ++j) {
    const int h = dsi[j] & (DSAE - 1);
    const float v = dsv[j];
    if (TRANSPOSED) {
      const unsigned short* wrow =
          (const unsigned short*)Wd_ + ((size_t)t * DSAE + h) * DIN;
#pragma unroll
      for (int i = 0; i < 3; ++i)
        acc[i] = fmaf(v, bf16tof(wrow[tid + 256 * i]), acc[i]);
    } else {
      const float* Wd = (const float*)Wd_;
#pragma unroll
      for (int i = 0; i < 3; ++i)
        acc[i] = fmaf(v, Wd[((size_t)t * DIN + tid + 256 * i) * DSAE + h], acc[i]);
    }
  }
  float sq = 0.f;
#pragma unroll
  for (int i = 0; i < 3; ++i) {
    const int d = tid + 256 * i;
    const float xv = x[(size_t)r * DIN + d];
    xhat[(size_t)r * DIN + d] = acc[i];
    const float e = acc[i] - xv;
    sq = fmaf(e, e, sq);
  }
  for (int off = 32; off; off >>= 1) sq += __shfl_down(sq, off);
  if ((tid & 63) == 0) rbuf[tid >> 6] = sq;
  __syncthreads();
  if (tid == 0)
    atomicAdd(loss, (rbuf[0] + rbuf[1] + rbuf[2] + rbuf[3]) * (1.0f / NROWS));
}

// ---------------- host ------------------------------------------------------
extern "C" void kernel_launch(void* const* d_in, const int* in_sizes, int n_in,
                              void* d_out, int out_size, void* d_ws, size_t ws_size,
                              hipStream_t stream) {
  const float* x    = (const float*)d_in[0];
  const float* Wenc = (const float*)d_in[1];
  const float* benc = (const float*)d_in[2];
  const float* Wdec = (const float*)d_in[3];
  const float* bdec = (const float*)d_in[4];

  float* out  = (float*)d_out;
  float* loss = out;
  float* xhat = out + 1;
  float* u    = out + 1 + (size_t)NROWS * DIN;  // (B,T,DSAE) == rows r

  float*          wsf  = (float*)d_ws;
  float*          xc   = wsf + OFF_XC;
  unsigned short* xcp  = (unsigned short*)(wsf + OFF_XCP);
  unsigned short* preb = (unsigned short*)(wsf + OFF_PREB);
  unsigned short* big  = (unsigned short*)(wsf + OFF_BIG);  // wt (bf16)
  const bool fast = ws_size >= WS_FAST_WORDS * sizeof(float);

  k_init<<<2816, 256, 0, stream>>>(x, bdec, xc, xcp, u, loss);
  k_encoder<<<512, 256, 0, stream>>>(xcp, Wenc, benc, preb);
  if (fast) {
    k_transpose<<<dim3(DSAE / 128, DIN / 128, T_SZ), 256, 0, stream>>>(Wdec, big);
    k_select_dec<true><<<NROWS, 256, 0, stream>>>(xc, Wenc, benc, preb, big,
                                                  x, bdec, u, xhat, loss);
  } else {
    k_select_dec<false><<<NROWS, 256, 0, stream>>>(xc, Wenc, benc, preb, Wdec,
                                                   x, bdec, u, xhat, loss);
  }
}